// Round 14
// baseline (903.175 us; speedup 1.0000x reference)
//
#include <hip/hip_runtime.h>
#include <math.h>

static __device__ __forceinline__ float sigf(float v) { return 1.0f / (1.0f + expf(-v)); }

using s8v = __attribute__((ext_vector_type(8))) short;   // 8 bf16 (4 VGPR)
using f4v = __attribute__((ext_vector_type(4))) float;   // MFMA acc

static __device__ __forceinline__ void splitf(float f, unsigned short& h, unsigned short& l) {
  unsigned u = __float_as_uint(f);
  unsigned short hb = (unsigned short)((u + 0x7FFFu + ((u >> 16) & 1u)) >> 16);
  float hf = __uint_as_float(((unsigned)hb) << 16);
  float lf = f - hf;
  unsigned ul = __float_as_uint(lf);
  unsigned short lb = (unsigned short)((ul + 0x7FFFu + ((ul >> 16) & 1u)) >> 16);
  h = hb; l = lb;
}

// ---------------------------------------------------------------------------
// Elementwise split: W f32 -> WH/WL bf16 (ushort). n4 = elems/4.
// ---------------------------------------------------------------------------
__global__ __launch_bounds__(256) void wsplit(
    const float* __restrict__ W, unsigned short* __restrict__ WH,
    unsigned short* __restrict__ WL, int n4)
{
  int i = blockIdx.x * 256 + threadIdx.x;
  if (i < n4) {
    float4 v = ((const float4*)W)[i];
    ushort4 h, l;
    splitf(v.x, h.x, l.x); splitf(v.y, h.y, l.y);
    splitf(v.z, h.z, l.z); splitf(v.w, h.w, l.w);
    ((ushort4*)WH)[i] = h;
    ((ushort4*)WL)[i] = l;
  }
}

// ---------------------------------------------------------------------------
// MFMA GEMM, A fp32 split on the fly, W pre-split. (fc_en1 fallback)
// C/out = act(A[M,K] @ W[N,K]^T + bias). Tile 128x64, BK=32, 4 waves.
// OSPLIT=1: write bf16 hi/lo pair (act applied first). act: 1=relu, 2=tanh.
// ---------------------------------------------------------------------------
template <int OSPLIT>
__global__ __launch_bounds__(256) void gemm_sf(
    const float* __restrict__ A,
    const unsigned short* __restrict__ WH, const unsigned short* __restrict__ WL,
    const float* __restrict__ bias, float* __restrict__ C,
    unsigned short* __restrict__ OH, unsigned short* __restrict__ OL,
    int M, int N, int K, int act)
{
  __shared__ unsigned short AsH[128 * 40];
  __shared__ unsigned short AsL[128 * 40];
  __shared__ unsigned short WsH[64 * 40];
  __shared__ unsigned short WsL[64 * 40];

  const int t = threadIdx.x;
  const int w = t >> 6, lane = t & 63;
  const int lrow = lane & 15, lk = (lane >> 4) * 8;
  const int m0 = blockIdx.x * 128, n0 = blockIdx.y * 64;

  f4v acc[2][4];
#pragma unroll
  for (int i = 0; i < 2; ++i)
#pragma unroll
    for (int j = 0; j < 4; ++j) acc[i][j] = (f4v){0.f, 0.f, 0.f, 0.f};

  for (int k0 = 0; k0 < K; k0 += 32) {
#pragma unroll
    for (int i = 0; i < 4; ++i) {
      int v = i * 256 + t;
      int row = v >> 3, kq = (v & 7) << 2;
      float4 a = *(const float4*)(A + (size_t)(m0 + row) * K + k0 + kq);
      ushort4 h4, l4;
      splitf(a.x, h4.x, l4.x); splitf(a.y, h4.y, l4.y);
      splitf(a.z, h4.z, l4.z); splitf(a.w, h4.w, l4.w);
      *(ushort4*)&AsH[row * 40 + kq] = h4;
      *(ushort4*)&AsL[row * 40 + kq] = l4;
    }
    {
      int row = t >> 2, q = (t & 3) * 8;
      *(s8v*)&WsH[row * 40 + q] = *(const s8v*)(WH + (size_t)(n0 + row) * K + k0 + q);
      *(s8v*)&WsL[row * 40 + q] = *(const s8v*)(WL + (size_t)(n0 + row) * K + k0 + q);
    }
    __syncthreads();

    s8v aH[2], aL[2], bH[4], bL[4];
#pragma unroll
    for (int mt = 0; mt < 2; ++mt) {
      int r = (w * 32 + mt * 16 + lrow) * 40 + lk;
      aH[mt] = *(const s8v*)&AsH[r];
      aL[mt] = *(const s8v*)&AsL[r];
    }
#pragma unroll
    for (int nt = 0; nt < 4; ++nt) {
      int r = (nt * 16 + lrow) * 40 + lk;
      bH[nt] = *(const s8v*)&WsH[r];
      bL[nt] = *(const s8v*)&WsL[r];
    }
#pragma unroll
    for (int mt = 0; mt < 2; ++mt)
#pragma unroll
      for (int nt = 0; nt < 4; ++nt) {
        acc[mt][nt] = __builtin_amdgcn_mfma_f32_16x16x32_bf16(aH[mt], bH[nt], acc[mt][nt], 0, 0, 0);
        acc[mt][nt] = __builtin_amdgcn_mfma_f32_16x16x32_bf16(aH[mt], bL[nt], acc[mt][nt], 0, 0, 0);
        acc[mt][nt] = __builtin_amdgcn_mfma_f32_16x16x32_bf16(aL[mt], bH[nt], acc[mt][nt], 0, 0, 0);
      }
    __syncthreads();
  }

#pragma unroll
  for (int mt = 0; mt < 2; ++mt)
#pragma unroll
    for (int nt = 0; nt < 4; ++nt) {
      int gcol = n0 + nt * 16 + lrow;
      float bv = bias[gcol];
#pragma unroll
      for (int r = 0; r < 4; ++r) {
        int grow = m0 + w * 32 + mt * 16 + (lane >> 4) * 4 + r;
        float v = acc[mt][nt][r] + bv;
        if (act == 1) v = fmaxf(v, 0.f);
        else if (act == 2) v = tanhf(v);
        if (OSPLIT) {
          unsigned short h, l;
          splitf(v, h, l);
          OH[(size_t)grow * N + gcol] = h;
          OL[(size_t)grow * N + gcol] = l;
        } else {
          C[(size_t)grow * N + gcol] = v;
        }
      }
    }
}

// ---------------------------------------------------------------------------
// MFMA GEMM, A AND W pre-split bf16. Same contract/tiling as gemm_sf.
// ---------------------------------------------------------------------------
template <int OSPLIT>
__global__ __launch_bounds__(256) void gemm_bb(
    const unsigned short* __restrict__ AH, const unsigned short* __restrict__ AL,
    const unsigned short* __restrict__ WH, const unsigned short* __restrict__ WL,
    const float* __restrict__ bias, float* __restrict__ C,
    unsigned short* __restrict__ OH, unsigned short* __restrict__ OL,
    int M, int N, int K, int act)
{
  __shared__ unsigned short AsH[128 * 40];
  __shared__ unsigned short AsL[128 * 40];
  __shared__ unsigned short WsH[64 * 40];
  __shared__ unsigned short WsL[64 * 40];

  const int t = threadIdx.x;
  const int w = t >> 6, lane = t & 63;
  const int lrow = lane & 15, lk = (lane >> 4) * 8;
  const int m0 = blockIdx.x * 128, n0 = blockIdx.y * 64;

  f4v acc[2][4];
#pragma unroll
  for (int i = 0; i < 2; ++i)
#pragma unroll
    for (int j = 0; j < 4; ++j) acc[i][j] = (f4v){0.f, 0.f, 0.f, 0.f};

  for (int k0 = 0; k0 < K; k0 += 32) {
#pragma unroll
    for (int i = 0; i < 2; ++i) {
      int v = i * 256 + t;
      int row = v >> 2, q = (v & 3) * 8;
      *(s8v*)&AsH[row * 40 + q] = *(const s8v*)(AH + (size_t)(m0 + row) * K + k0 + q);
      *(s8v*)&AsL[row * 40 + q] = *(const s8v*)(AL + (size_t)(m0 + row) * K + k0 + q);
    }
    {
      int row = t >> 2, q = (t & 3) * 8;
      *(s8v*)&WsH[row * 40 + q] = *(const s8v*)(WH + (size_t)(n0 + row) * K + k0 + q);
      *(s8v*)&WsL[row * 40 + q] = *(const s8v*)(WL + (size_t)(n0 + row) * K + k0 + q);
    }
    __syncthreads();

    s8v aH[2], aL[2], bH[4], bL[4];
#pragma unroll
    for (int mt = 0; mt < 2; ++mt) {
      int r = (w * 32 + mt * 16 + lrow) * 40 + lk;
      aH[mt] = *(const s8v*)&AsH[r];
      aL[mt] = *(const s8v*)&AsL[r];
    }
#pragma unroll
    for (int nt = 0; nt < 4; ++nt) {
      int r = (nt * 16 + lrow) * 40 + lk;
      bH[nt] = *(const s8v*)&WsH[r];
      bL[nt] = *(const s8v*)&WsL[r];
    }
#pragma unroll
    for (int mt = 0; mt < 2; ++mt)
#pragma unroll
      for (int nt = 0; nt < 4; ++nt) {
        acc[mt][nt] = __builtin_amdgcn_mfma_f32_16x16x32_bf16(aH[mt], bH[nt], acc[mt][nt], 0, 0, 0);
        acc[mt][nt] = __builtin_amdgcn_mfma_f32_16x16x32_bf16(aH[mt], bL[nt], acc[mt][nt], 0, 0, 0);
        acc[mt][nt] = __builtin_amdgcn_mfma_f32_16x16x32_bf16(aL[mt], bH[nt], acc[mt][nt], 0, 0, 0);
      }
    __syncthreads();
  }

#pragma unroll
  for (int mt = 0; mt < 2; ++mt)
#pragma unroll
    for (int nt = 0; nt < 4; ++nt) {
      int gcol = n0 + nt * 16 + lrow;
      float bv = bias[gcol];
#pragma unroll
      for (int r = 0; r < 4; ++r) {
        int grow = m0 + w * 32 + mt * 16 + (lane >> 4) * 4 + r;
        float v = acc[mt][nt][r] + bv;
        if (act == 1) v = fmaxf(v, 0.f);
        else if (act == 2) v = tanhf(v);
        if (OSPLIT) {
          unsigned short h, l;
          splitf(v, h, l);
          OH[(size_t)grow * N + gcol] = h;
          OL[(size_t)grow * N + gcol] = l;
        } else {
          C[(size_t)grow * N + gcol] = v;
        }
      }
    }
}

// ---------------------------------------------------------------------------
// Pack LSTM weights: wP[j][k][s] = w[(s*256+j)*256 + k] (s = i,f,g,o);
// bP[j][s] = bih[s*256+j] + bhh[s*256+j].  grid 256 (j), block 256 (k).
// ---------------------------------------------------------------------------
__global__ __launch_bounds__(256) void prep_pack(
    const float* __restrict__ wih, const float* __restrict__ whh,
    const float* __restrict__ bih, const float* __restrict__ bhh,
    float* __restrict__ wihP, float* __restrict__ whhP, float* __restrict__ bP)
{
  const int j = blockIdx.x, k = threadIdx.x;
  float4 a, c;
  a.x = wih[(0 * 256 + j) * 256 + k];
  a.y = wih[(1 * 256 + j) * 256 + k];
  a.z = wih[(2 * 256 + j) * 256 + k];
  a.w = wih[(3 * 256 + j) * 256 + k];
  *(float4*)&wihP[((size_t)j * 256 + k) * 4] = a;
  c.x = whh[(0 * 256 + j) * 256 + k];
  c.y = whh[(1 * 256 + j) * 256 + k];
  c.z = whh[(2 * 256 + j) * 256 + k];
  c.w = whh[(3 * 256 + j) * 256 + k];
  *(float4*)&whhP[((size_t)j * 256 + k) * 4] = c;
  if (k < 4) bP[j * 4 + k] = bih[k * 256 + j] + bhh[k * 256 + j];
}

// ---------------------------------------------------------------------------
// Per-slab 256x256 transpose (f32): out[t][c][r] = in[t][r][c].
// ---------------------------------------------------------------------------
__global__ __launch_bounds__(256) void transpose256(
    const float* __restrict__ in, float* __restrict__ out)
{
  const int t = blockIdx.x, c4 = blockIdx.y;
  const int r = threadIdx.x;
  float4 v = *(const float4*)(in + ((size_t)t * 256 + r) * 256 + c4 * 4);
  float* op = out + (size_t)t * 65536 + (size_t)(c4 * 4) * 256 + r;
  op[0]   = v.x;
  op[256] = v.y;
  op[512] = v.z;
  op[768] = v.w;
}

// ---------------------------------------------------------------------------
// Transpose + bf16-split: outH/L[t][c][r] = split(in[t][r][c]).
// ---------------------------------------------------------------------------
__global__ __launch_bounds__(256) void transpose256s(
    const float* __restrict__ in, unsigned short* __restrict__ outH,
    unsigned short* __restrict__ outL)
{
  const int t = blockIdx.x, c4 = blockIdx.y;
  const int r = threadIdx.x;
  float4 v = *(const float4*)(in + ((size_t)t * 256 + r) * 256 + c4 * 4);
  ushort4 h, l;
  splitf(v.x, h.x, l.x); splitf(v.y, h.y, l.y);
  splitf(v.z, h.z, l.z); splitf(v.w, h.w, l.w);
  size_t o = (size_t)t * 65536 + (size_t)(c4 * 4) * 256 + r;
  outH[o] = h.x; outH[o + 256] = h.y; outH[o + 512] = h.z; outH[o + 768] = h.w;
  outL[o] = l.x; outL[o + 256] = l.y; outL[o + 512] = l.z; outL[o + 768] = l.w;
}

// ---------------------------------------------------------------------------
// Multi-slot LSTM cell kernel with k-split=4 (scalar-path preserving).
// Slot = blockIdx.x>>8; inner 256 blocks = bg(4)-major x jg(64).
// Block 1024 thr = 16 waves: wave = kq(4) x jwv(4). kq and jw are routed
// through readfirstlane so weight/base pointers stay SGPR and the k-loop
// has COMPILE-TIME bounds (0..64) -> s_load + immediate-offset vector loads.
// kq>=1 partials combined via LDS; kq=0 waves run the epilogue.
// All h/x in [k][b] layout; c in-place [j][b].
// ---------------------------------------------------------------------------
struct CellSlot {
  const float* x;     // [256][256] (k,b) or null
  const float* wih;   // [j][256][4]
  const float* whh;   // [j][256][4]
  const float* bias;  // [j][4]
  const float* hin;   // [256][256] (k,b)
  float* c;           // [256][256] (j,b) in-place
  float* hout;        // [256][256] (j,b)
  float* hcopy;       // optional
  int hasx;
};
struct CellArgs { CellSlot s[3]; };

__global__ __launch_bounds__(1024) void cell_multi(CellArgs args)
{
  __shared__ float part[3][4][64][4];  // [kq-1][jwv][lane][gate]
  const CellSlot S = args.s[blockIdx.x >> 8];
  const int inner = blockIdx.x & 255;
  const int jg = inner & 63, bg = inner >> 6;
  const int t = threadIdx.x;
  const int lane = t & 63;
  const int wave = t >> 6;                                    // 0..15
  const int jwv = wave & 3;
  const int kq = __builtin_amdgcn_readfirstlane(wave >> 2);   // SGPR 0..3
  const int b = bg * 64 + lane;

  const int jw = __builtin_amdgcn_readfirstlane(jg * 4 + jwv); // SGPR
  // Scalar base pointers offset by this wave's k-quarter:
  const float4* wh = (const float4*)(S.whh + (size_t)jw * 1024) + kq * 64;
  const float4* wi = (const float4*)(S.wih + (size_t)jw * 1024) + kq * 64;
  const float* hcol = S.hin + (size_t)kq * 64 * 256 + b;

  float4 acc;
  if (kq == 0) acc = *(const float4*)(S.bias + jw * 4);
  else         acc = (float4){0.f, 0.f, 0.f, 0.f};

  if (S.hasx) {
    const float* xcol = S.x + (size_t)kq * 64 * 256 + b;
#pragma unroll 8
    for (int k = 0; k < 64; ++k) {
      const float hv = hcol[k * 256];
      const float4 wv = wh[k];
      acc.x = fmaf(hv, wv.x, acc.x);
      acc.y = fmaf(hv, wv.y, acc.y);
      acc.z = fmaf(hv, wv.z, acc.z);
      acc.w = fmaf(hv, wv.w, acc.w);
      const float xv = xcol[k * 256];
      const float4 vv = wi[k];
      acc.x = fmaf(xv, vv.x, acc.x);
      acc.y = fmaf(xv, vv.y, acc.y);
      acc.z = fmaf(xv, vv.z, acc.z);
      acc.w = fmaf(xv, vv.w, acc.w);
    }
  } else {
#pragma unroll 8
    for (int k = 0; k < 64; ++k) {
      const float hv = hcol[k * 256];
      const float4 wv = wh[k];
      acc.x = fmaf(hv, wv.x, acc.x);
      acc.y = fmaf(hv, wv.y, acc.y);
      acc.z = fmaf(hv, wv.z, acc.z);
      acc.w = fmaf(hv, wv.w, acc.w);
    }
  }

  if (kq >= 1) *(float4*)&part[kq - 1][jwv][lane][0] = acc;
  __syncthreads();
  if (kq == 0) {
    const float4 p0 = *(const float4*)&part[0][jwv][lane][0];
    const float4 p1 = *(const float4*)&part[1][jwv][lane][0];
    const float4 p2 = *(const float4*)&part[2][jwv][lane][0];
    acc.x += p0.x + p1.x + p2.x;
    acc.y += p0.y + p1.y + p2.y;
    acc.z += p0.z + p1.z + p2.z;
    acc.w += p0.w + p1.w + p2.w;

    const int idx = jw * 256 + b;
    const float cold = S.c[idx];
    const float ig = sigf(acc.x), fg = sigf(acc.y);
    const float gg = tanhf(acc.z), og = sigf(acc.w);
    const float cn = fg * cold + ig * gg;
    const float hn = og * tanhf(cn);
    S.c[idx] = cn;
    S.hout[idx] = hn;
    if (S.hcopy) S.hcopy[idx] = hn;
  }
}

// ---------------------------------------------------------------------------

extern "C" void kernel_launch(void* const* d_in, const int* in_sizes, int n_in,
                              void* d_out, int out_size, void* d_ws, size_t ws_size,
                              hipStream_t stream)
{
  const float* x_in  = (const float*)d_in[0];
  const float* w_en1 = (const float*)d_in[1];
  const float* b_en1 = (const float*)d_in[2];
  const float* w_en2 = (const float*)d_in[3];
  const float* b_en2 = (const float*)d_in[4];
  const float* cw[6][4];
  for (int i = 0; i < 6; ++i)
    for (int j = 0; j < 4; ++j) cw[i][j] = (const float*)d_in[5 + i * 4 + j];
  const float* w_de1 = (const float*)d_in[29];
  const float* b_de1 = (const float*)d_in[30];
  const float* w_de2 = (const float*)d_in[31];
  const float* b_de2 = (const float*)d_in[32];
  float* out = (float*)d_out;

  // ---- workspace layout (~87 MB base; +84 MB XH/XL gated) ----
  float* fs   = (float*)d_ws;
  float* wihP = fs;                        // 6 * 262144 f
  float* whhP = wihP + 6 * 262144;         // 6 * 262144 f
  float* bP   = whhP + 6 * 262144;         // 6 * 1024 f
  float* hb   = bP + 6 * 1024;             // 12 * 65536 f
  float* cb   = hb + 12 * 65536;           // 6 * 65536 f
  float* H3T  = cb + 6 * 65536;            // 10 * 65536 f
  float* z2   = H3T + 10 * 65536;          // 1,310,720 f
  float* z2T  = z2 + 1310720;              // 1,310,720 f
  unsigned short* us = (unsigned short*)(z2T + 1310720);
  unsigned short* WEN1H = us;              us += 4194304;
  unsigned short* WEN1L = us;              us += 4194304;
  unsigned short* WEN2H = us;              us += 262144;
  unsigned short* WEN2L = us;              us += 262144;
  unsigned short* WDE1H = us;              us += 262144;
  unsigned short* WDE1L = us;              us += 262144;
  unsigned short* WDE2H = us;              us += 4194304;
  unsigned short* WDE2L = us;              us += 4194304;
  unsigned short* Z1H   = us;              us += 5242880;
  unsigned short* Z1L   = us;              us += 5242880;
  unsigned short* XH    = us;              us += 20971520;  // gated
  unsigned short* XL    = us;              us += 20971520;  // gated
  const size_t need_big = (size_t)((char*)us - (char*)d_ws);
  const bool big = ws_size >= need_big;
  // Y1/H3 alias the (dead-by-then) Z1 region:
  unsigned short* H3H = Z1H;
  unsigned short* H3L = Z1H + 655360;
  unsigned short* Y1H = Z1H + 1310720;
  unsigned short* Y1L = Z1H + 1310720 + 2621440;

  // ---- prep: cell packing, weight splits, state zero (every call) ----
  for (int i = 0; i < 6; ++i)
    prep_pack<<<256, 256, 0, stream>>>(cw[i][0], cw[i][1], cw[i][2], cw[i][3],
                                       wihP + i * 262144, whhP + i * 262144,
                                       bP + i * 1024);
  wsplit<<<4096, 256, 0, stream>>>(w_en1, WEN1H, WEN1L, 1048576);
  wsplit<<<256, 256, 0, stream>>>(w_en2, WEN2H, WEN2L, 65536);
  wsplit<<<256, 256, 0, stream>>>(w_de1, WDE1H, WDE1L, 65536);
  wsplit<<<4096, 256, 0, stream>>>(w_de2, WDE2H, WDE2L, 1048576);
  if (big)
    wsplit<<<20480, 256, 0, stream>>>(x_in, XH, XL, 5242880);
  hipMemsetAsync(hb, 0, (size_t)18 * 65536 * sizeof(float), stream);

  // ---- encoder feedforward (all MFMA) ----
  if (big)
    gemm_bb<1><<<dim3(40, 16), 256, 0, stream>>>(
        XH, XL, WEN1H, WEN1L, b_en1, nullptr, Z1H, Z1L, 5120, 1024, 4096, 1);
  else
    gemm_sf<1><<<dim3(40, 16), 256, 0, stream>>>(
        x_in, WEN1H, WEN1L, b_en1, nullptr, Z1H, Z1L, 5120, 1024, 4096, 1);
  gemm_bb<0><<<dim3(40, 4), 256, 0, stream>>>(
      Z1H, Z1L, WEN2H, WEN2L, b_en2, z2, nullptr, nullptr, 5120, 256, 1024, 1);
  transpose256<<<dim3(20, 64), 256, 0, stream>>>(z2, z2T);

  // ---- recurrence: layer-pipelined cell launches (k-split=4 blocks) ----
  int pp[6] = {0, 0, 0, 0, 0, 0};
  auto HBuf = [&](int l, int p) { return hb + (size_t)(l * 2 + p) * 65536; };
  auto CBuf = [&](int l) { return cb + (size_t)l * 65536; };
  auto WI = [&](int l) { return wihP + (size_t)l * 262144; };
  auto WHp = [&](int l) { return whhP + (size_t)l * 262144; };
  auto BB = [&](int l) { return bP + (size_t)l * 1024; };

  for (int s = 0; s <= 21; ++s) {
    CellArgs a; int n = 0; int tog[3]; int nt = 0;
    if (s < 20) {
      a.s[n++] = {z2T + (size_t)s * 65536, WI(0), WHp(0), BB(0),
                  HBuf(0, pp[0]), CBuf(0), HBuf(0, pp[0] ^ 1), nullptr, 1};
      tog[nt++] = 0;
    }
    if (s >= 1 && s <= 20) {
      a.s[n++] = {HBuf(0, pp[0]), WI(1), WHp(1), BB(1),
                  HBuf(1, pp[1]), CBuf(1), HBuf(1, pp[1] ^ 1), nullptr, 1};
      tog[nt++] = 1;
    }
    if (s >= 2) {
      a.s[n++] = {HBuf(1, pp[1]), WI(2), WHp(2), BB(2),
                  HBuf(2, pp[2]), CBuf(2), HBuf(2, pp[2] ^ 1), nullptr, 1};
      tog[nt++] = 2;
    }
    cell_multi<<<n * 256, 1024, 0, stream>>>(a);
    for (int i = 0; i < nt; ++i) pp[tog[i]] ^= 1;
  }

  for (int s = 0; s <= 11; ++s) {
    CellArgs a; int n = 0; int tog[3]; int nt = 0;
    if (s < 10) {
      const float* h1in = (s == 0) ? HBuf(2, pp[2]) : HBuf(3, pp[3]);
      a.s[n++] = {nullptr, WI(3), WHp(3), BB(3),
                  h1in, CBuf(3), HBuf(3, pp[3] ^ 1), nullptr, 0};
      tog[nt++] = 3;
    }
    if (s >= 1 && s <= 10) {
      a.s[n++] = {HBuf(3, pp[3]), WI(4), WHp(4), BB(4),
                  HBuf(4, pp[4]), CBuf(4), HBuf(4, pp[4] ^ 1), nullptr, 1};
      tog[nt++] = 4;
    }
    if (s >= 2) {
      a.s[n++] = {HBuf(4, pp[4]), WI(5), WHp(5), BB(5),
                  HBuf(5, pp[5]), CBuf(5), HBuf(5, pp[5] ^ 1),
                  H3T + (size_t)(s - 2) * 65536, 1};
      tog[nt++] = 5;
    }
    cell_multi<<<n * 256, 1024, 0, stream>>>(a);
    for (int i = 0; i < nt; ++i) pp[tog[i]] ^= 1;
  }

  // ---- decoder output FCs (all MFMA) ----
  transpose256s<<<dim3(10, 64), 256, 0, stream>>>(H3T, H3H, H3L);  // [s][j][b]->[s][b][j]
  gemm_bb<1><<<dim3(20, 16), 256, 0, stream>>>(
      H3H, H3L, WDE1H, WDE1L, b_de1, nullptr, Y1H, Y1L, 2560, 1024, 256, 1);
  gemm_bb<0><<<dim3(20, 64), 256, 0, stream>>>(
      Y1H, Y1L, WDE2H, WDE2L, b_de2, out, nullptr, nullptr, 2560, 4096, 1024, 2);

  (void)in_sizes; (void)n_in; (void)out_size; (void)ws_size;
}

// Round 15
// 854.696 us; speedup vs baseline: 1.0567x; 1.0567x over previous
//
#include <hip/hip_runtime.h>
#include <math.h>

static __device__ __forceinline__ float sigf(float v) { return 1.0f / (1.0f + expf(-v)); }

using s8v = __attribute__((ext_vector_type(8))) short;   // 8 bf16 (4 VGPR)
using f4v = __attribute__((ext_vector_type(4))) float;   // MFMA acc

static __device__ __forceinline__ void splitf(float f, unsigned short& h, unsigned short& l) {
  unsigned u = __float_as_uint(f);
  unsigned short hb = (unsigned short)((u + 0x7FFFu + ((u >> 16) & 1u)) >> 16);
  float hf = __uint_as_float(((unsigned)hb) << 16);
  float lf = f - hf;
  unsigned ul = __float_as_uint(lf);
  unsigned short lb = (unsigned short)((ul + 0x7FFFu + ((ul >> 16) & 1u)) >> 16);
  h = hb; l = lb;
}

// Fast float4 -> packed bf16 hi/lo via HW v_cvt_pk_bf16_f32 (RTNE).
// hOut = {bf16(y):bf16(x), bf16(w):bf16(z)}, lOut likewise for residuals.
static __device__ __forceinline__ void splitf4(float4 a, uint2& hOut, uint2& lOut) {
  unsigned hxy, hzw;
  asm("v_cvt_pk_bf16_f32 %0, %1, %2" : "=v"(hxy) : "v"(a.x), "v"(a.y));
  asm("v_cvt_pk_bf16_f32 %0, %1, %2" : "=v"(hzw) : "v"(a.z), "v"(a.w));
  float hx = __uint_as_float(hxy << 16);
  float hy = __uint_as_float(hxy & 0xFFFF0000u);
  float hz = __uint_as_float(hzw << 16);
  float hw = __uint_as_float(hzw & 0xFFFF0000u);
  unsigned lxy, lzw;
  asm("v_cvt_pk_bf16_f32 %0, %1, %2" : "=v"(lxy) : "v"(a.x - hx), "v"(a.y - hy));
  asm("v_cvt_pk_bf16_f32 %0, %1, %2" : "=v"(lzw) : "v"(a.z - hz), "v"(a.w - hw));
  hOut.x = hxy; hOut.y = hzw;
  lOut.x = lxy; lOut.y = lzw;
}

// ---------------------------------------------------------------------------
// One-time weight split: W f32 -> WH/WL bf16 (ushort). n4 = elems/4.
// ---------------------------------------------------------------------------
__global__ __launch_bounds__(256) void wsplit(
    const float* __restrict__ W, unsigned short* __restrict__ WH,
    unsigned short* __restrict__ WL, int n4)
{
  int i = blockIdx.x * 256 + threadIdx.x;
  if (i < n4) {
    float4 v = ((const float4*)W)[i];
    ushort4 h, l;
    splitf(v.x, h.x, l.x); splitf(v.y, h.y, l.y);
    splitf(v.z, h.z, l.z); splitf(v.w, h.w, l.w);
    ((ushort4*)WH)[i] = h;
    ((ushort4*)WL)[i] = l;
  }
}

// ---------------------------------------------------------------------------
// MFMA GEMM, A fp32 split on the fly (HW cvt_pk), W pre-split. (fc_en1)
// C/out = act(A[M,K] @ W[N,K]^T + bias). Tile 128x64, BK=32, 4 waves.
// OSPLIT=1: write bf16 hi/lo pair (act applied first). act: 1=relu, 2=tanh.
// ---------------------------------------------------------------------------
template <int OSPLIT>
__global__ __launch_bounds__(256) void gemm_sf(
    const float* __restrict__ A,
    const unsigned short* __restrict__ WH, const unsigned short* __restrict__ WL,
    const float* __restrict__ bias, float* __restrict__ C,
    unsigned short* __restrict__ OH, unsigned short* __restrict__ OL,
    int M, int N, int K, int act)
{
  __shared__ unsigned short AsH[128 * 40];
  __shared__ unsigned short AsL[128 * 40];
  __shared__ unsigned short WsH[64 * 40];
  __shared__ unsigned short WsL[64 * 40];

  const int t = threadIdx.x;
  const int w = t >> 6, lane = t & 63;
  const int lrow = lane & 15, lk = (lane >> 4) * 8;
  const int m0 = blockIdx.x * 128, n0 = blockIdx.y * 64;

  f4v acc[2][4];
#pragma unroll
  for (int i = 0; i < 2; ++i)
#pragma unroll
    for (int j = 0; j < 4; ++j) acc[i][j] = (f4v){0.f, 0.f, 0.f, 0.f};

  for (int k0 = 0; k0 < K; k0 += 32) {
#pragma unroll
    for (int i = 0; i < 4; ++i) {
      int v = i * 256 + t;
      int row = v >> 3, kq = (v & 7) << 2;   // kq in {0,4,...,28}: 8B-aligned
      float4 a = *(const float4*)(A + (size_t)(m0 + row) * K + k0 + kq);
      uint2 h2, l2;
      splitf4(a, h2, l2);
      *(uint2*)&AsH[row * 40 + kq] = h2;
      *(uint2*)&AsL[row * 40 + kq] = l2;
    }
    {
      int row = t >> 2, q = (t & 3) * 8;
      *(s8v*)&WsH[row * 40 + q] = *(const s8v*)(WH + (size_t)(n0 + row) * K + k0 + q);
      *(s8v*)&WsL[row * 40 + q] = *(const s8v*)(WL + (size_t)(n0 + row) * K + k0 + q);
    }
    __syncthreads();

    s8v aH[2], aL[2], bH[4], bL[4];
#pragma unroll
    for (int mt = 0; mt < 2; ++mt) {
      int r = (w * 32 + mt * 16 + lrow) * 40 + lk;
      aH[mt] = *(const s8v*)&AsH[r];
      aL[mt] = *(const s8v*)&AsL[r];
    }
#pragma unroll
    for (int nt = 0; nt < 4; ++nt) {
      int r = (nt * 16 + lrow) * 40 + lk;
      bH[nt] = *(const s8v*)&WsH[r];
      bL[nt] = *(const s8v*)&WsL[r];
    }
#pragma unroll
    for (int mt = 0; mt < 2; ++mt)
#pragma unroll
      for (int nt = 0; nt < 4; ++nt) {
        acc[mt][nt] = __builtin_amdgcn_mfma_f32_16x16x32_bf16(aH[mt], bH[nt], acc[mt][nt], 0, 0, 0);
        acc[mt][nt] = __builtin_amdgcn_mfma_f32_16x16x32_bf16(aH[mt], bL[nt], acc[mt][nt], 0, 0, 0);
        acc[mt][nt] = __builtin_amdgcn_mfma_f32_16x16x32_bf16(aL[mt], bH[nt], acc[mt][nt], 0, 0, 0);
      }
    __syncthreads();
  }

#pragma unroll
  for (int mt = 0; mt < 2; ++mt)
#pragma unroll
    for (int nt = 0; nt < 4; ++nt) {
      int gcol = n0 + nt * 16 + lrow;
      float bv = bias[gcol];
#pragma unroll
      for (int r = 0; r < 4; ++r) {
        int grow = m0 + w * 32 + mt * 16 + (lane >> 4) * 4 + r;
        float v = acc[mt][nt][r] + bv;
        if (act == 1) v = fmaxf(v, 0.f);
        else if (act == 2) v = tanhf(v);
        if (OSPLIT) {
          unsigned short h, l;
          splitf(v, h, l);
          OH[(size_t)grow * N + gcol] = h;
          OL[(size_t)grow * N + gcol] = l;
        } else {
          C[(size_t)grow * N + gcol] = v;
        }
      }
    }
}

// ---------------------------------------------------------------------------
// MFMA GEMM, A AND W pre-split bf16. Same contract/tiling as gemm_sf.
// ---------------------------------------------------------------------------
template <int OSPLIT>
__global__ __launch_bounds__(256) void gemm_bb(
    const unsigned short* __restrict__ AH, const unsigned short* __restrict__ AL,
    const unsigned short* __restrict__ WH, const unsigned short* __restrict__ WL,
    const float* __restrict__ bias, float* __restrict__ C,
    unsigned short* __restrict__ OH, unsigned short* __restrict__ OL,
    int M, int N, int K, int act)
{
  __shared__ unsigned short AsH[128 * 40];
  __shared__ unsigned short AsL[128 * 40];
  __shared__ unsigned short WsH[64 * 40];
  __shared__ unsigned short WsL[64 * 40];

  const int t = threadIdx.x;
  const int w = t >> 6, lane = t & 63;
  const int lrow = lane & 15, lk = (lane >> 4) * 8;
  const int m0 = blockIdx.x * 128, n0 = blockIdx.y * 64;

  f4v acc[2][4];
#pragma unroll
  for (int i = 0; i < 2; ++i)
#pragma unroll
    for (int j = 0; j < 4; ++j) acc[i][j] = (f4v){0.f, 0.f, 0.f, 0.f};

  for (int k0 = 0; k0 < K; k0 += 32) {
#pragma unroll
    for (int i = 0; i < 2; ++i) {
      int v = i * 256 + t;
      int row = v >> 2, q = (v & 3) * 8;
      *(s8v*)&AsH[row * 40 + q] = *(const s8v*)(AH + (size_t)(m0 + row) * K + k0 + q);
      *(s8v*)&AsL[row * 40 + q] = *(const s8v*)(AL + (size_t)(m0 + row) * K + k0 + q);
    }
    {
      int row = t >> 2, q = (t & 3) * 8;
      *(s8v*)&WsH[row * 40 + q] = *(const s8v*)(WH + (size_t)(n0 + row) * K + k0 + q);
      *(s8v*)&WsL[row * 40 + q] = *(const s8v*)(WL + (size_t)(n0 + row) * K + k0 + q);
    }
    __syncthreads();

    s8v aH[2], aL[2], bH[4], bL[4];
#pragma unroll
    for (int mt = 0; mt < 2; ++mt) {
      int r = (w * 32 + mt * 16 + lrow) * 40 + lk;
      aH[mt] = *(const s8v*)&AsH[r];
      aL[mt] = *(const s8v*)&AsL[r];
    }
#pragma unroll
    for (int nt = 0; nt < 4; ++nt) {
      int r = (nt * 16 + lrow) * 40 + lk;
      bH[nt] = *(const s8v*)&WsH[r];
      bL[nt] = *(const s8v*)&WsL[r];
    }
#pragma unroll
    for (int mt = 0; mt < 2; ++mt)
#pragma unroll
      for (int nt = 0; nt < 4; ++nt) {
        acc[mt][nt] = __builtin_amdgcn_mfma_f32_16x16x32_bf16(aH[mt], bH[nt], acc[mt][nt], 0, 0, 0);
        acc[mt][nt] = __builtin_amdgcn_mfma_f32_16x16x32_bf16(aH[mt], bL[nt], acc[mt][nt], 0, 0, 0);
        acc[mt][nt] = __builtin_amdgcn_mfma_f32_16x16x32_bf16(aL[mt], bH[nt], acc[mt][nt], 0, 0, 0);
      }
    __syncthreads();
  }

#pragma unroll
  for (int mt = 0; mt < 2; ++mt)
#pragma unroll
    for (int nt = 0; nt < 4; ++nt) {
      int gcol = n0 + nt * 16 + lrow;
      float bv = bias[gcol];
#pragma unroll
      for (int r = 0; r < 4; ++r) {
        int grow = m0 + w * 32 + mt * 16 + (lane >> 4) * 4 + r;
        float v = acc[mt][nt][r] + bv;
        if (act == 1) v = fmaxf(v, 0.f);
        else if (act == 2) v = tanhf(v);
        if (OSPLIT) {
          unsigned short h, l;
          splitf(v, h, l);
          OH[(size_t)grow * N + gcol] = h;
          OL[(size_t)grow * N + gcol] = l;
        } else {
          C[(size_t)grow * N + gcol] = v;
        }
      }
    }
}

// ---------------------------------------------------------------------------
// Pack LSTM weights: wP[j][k][s] = w[(s*256+j)*256 + k] (s = i,f,g,o);
// bP[j][s] = bih[s*256+j] + bhh[s*256+j].  grid 256 (j), block 256 (k).
// ---------------------------------------------------------------------------
__global__ __launch_bounds__(256) void prep_pack(
    const float* __restrict__ wih, const float* __restrict__ whh,
    const float* __restrict__ bih, const float* __restrict__ bhh,
    float* __restrict__ wihP, float* __restrict__ whhP, float* __restrict__ bP)
{
  const int j = blockIdx.x, k = threadIdx.x;
  float4 a, c;
  a.x = wih[(0 * 256 + j) * 256 + k];
  a.y = wih[(1 * 256 + j) * 256 + k];
  a.z = wih[(2 * 256 + j) * 256 + k];
  a.w = wih[(3 * 256 + j) * 256 + k];
  *(float4*)&wihP[((size_t)j * 256 + k) * 4] = a;
  c.x = whh[(0 * 256 + j) * 256 + k];
  c.y = whh[(1 * 256 + j) * 256 + k];
  c.z = whh[(2 * 256 + j) * 256 + k];
  c.w = whh[(3 * 256 + j) * 256 + k];
  *(float4*)&whhP[((size_t)j * 256 + k) * 4] = c;
  if (k < 4) bP[j * 4 + k] = bih[k * 256 + j] + bhh[k * 256 + j];
}

// ---------------------------------------------------------------------------
// Per-slab 256x256 transpose (f32): out[t][c][r] = in[t][r][c].
// ---------------------------------------------------------------------------
__global__ __launch_bounds__(256) void transpose256(
    const float* __restrict__ in, float* __restrict__ out)
{
  const int t = blockIdx.x, c4 = blockIdx.y;
  const int r = threadIdx.x;
  float4 v = *(const float4*)(in + ((size_t)t * 256 + r) * 256 + c4 * 4);
  float* op = out + (size_t)t * 65536 + (size_t)(c4 * 4) * 256 + r;
  op[0]   = v.x;
  op[256] = v.y;
  op[512] = v.z;
  op[768] = v.w;
}

// ---------------------------------------------------------------------------
// Transpose + bf16-split: outH/L[t][c][r] = split(in[t][r][c]).
// ---------------------------------------------------------------------------
__global__ __launch_bounds__(256) void transpose256s(
    const float* __restrict__ in, unsigned short* __restrict__ outH,
    unsigned short* __restrict__ outL)
{
  const int t = blockIdx.x, c4 = blockIdx.y;
  const int r = threadIdx.x;
  float4 v = *(const float4*)(in + ((size_t)t * 256 + r) * 256 + c4 * 4);
  ushort4 h, l;
  splitf(v.x, h.x, l.x); splitf(v.y, h.y, l.y);
  splitf(v.z, h.z, l.z); splitf(v.w, h.w, l.w);
  size_t o = (size_t)t * 65536 + (size_t)(c4 * 4) * 256 + r;
  outH[o] = h.x; outH[o + 256] = h.y; outH[o + 512] = h.z; outH[o + 768] = h.w;
  outL[o] = l.x; outL[o + 256] = l.y; outL[o + 512] = l.z; outL[o + 768] = l.w;
}

// ---------------------------------------------------------------------------
// Multi-slot LSTM cell kernel with k-split=2 (scalar-path preserving).
// Slot = blockIdx.x>>8; inner 256 blocks = bg(4)-major x jg(64).
// Block 512 thr = 8 waves: wave = kh(2) x jwv(4). kh and jw are routed
// through readfirstlane so weight/base pointers stay SGPR and the k-loop
// has COMPILE-TIME bounds (0..128) -> s_load + immediate-offset vector loads.
// kh=1 partials combined via LDS; kh=0 waves run the epilogue.
// All h/x in [k][b] layout; c in-place [j][b].
// ---------------------------------------------------------------------------
struct CellSlot {
  const float* x;     // [256][256] (k,b) or null
  const float* wih;   // [j][256][4]
  const float* whh;   // [j][256][4]
  const float* bias;  // [j][4]
  const float* hin;   // [256][256] (k,b)
  float* c;           // [256][256] (j,b) in-place
  float* hout;        // [256][256] (j,b)
  float* hcopy;       // optional
  int hasx;
};
struct CellArgs { CellSlot s[3]; };

__global__ __launch_bounds__(512) void cell_multi(CellArgs args)
{
  __shared__ float part[4][64][4];  // [jwv][lane][gate]
  const CellSlot S = args.s[blockIdx.x >> 8];
  const int inner = blockIdx.x & 255;
  const int jg = inner & 63, bg = inner >> 6;
  const int t = threadIdx.x;
  const int lane = t & 63;
  const int wave = t >> 6;
  const int jwv = wave & 3;
  const int kh = __builtin_amdgcn_readfirstlane(wave >> 2);   // SGPR
  const int b = bg * 64 + lane;

  const int jw = __builtin_amdgcn_readfirstlane(jg * 4 + jwv); // SGPR
  // Scalar base pointers offset by this wave's k-half:
  const float4* wh = (const float4*)(S.whh + (size_t)jw * 1024) + kh * 128;
  const float4* wi = (const float4*)(S.wih + (size_t)jw * 1024) + kh * 128;
  const float* hcol = S.hin + (size_t)kh * 128 * 256 + b;

  float4 acc;
  if (kh == 0) acc = *(const float4*)(S.bias + jw * 4);
  else         acc = (float4){0.f, 0.f, 0.f, 0.f};

  if (S.hasx) {
    const float* xcol = S.x + (size_t)kh * 128 * 256 + b;
#pragma unroll 8
    for (int k = 0; k < 128; ++k) {
      const float hv = hcol[k * 256];
      const float4 wv = wh[k];
      acc.x = fmaf(hv, wv.x, acc.x);
      acc.y = fmaf(hv, wv.y, acc.y);
      acc.z = fmaf(hv, wv.z, acc.z);
      acc.w = fmaf(hv, wv.w, acc.w);
      const float xv = xcol[k * 256];
      const float4 vv = wi[k];
      acc.x = fmaf(xv, vv.x, acc.x);
      acc.y = fmaf(xv, vv.y, acc.y);
      acc.z = fmaf(xv, vv.z, acc.z);
      acc.w = fmaf(xv, vv.w, acc.w);
    }
  } else {
#pragma unroll 8
    for (int k = 0; k < 128; ++k) {
      const float hv = hcol[k * 256];
      const float4 wv = wh[k];
      acc.x = fmaf(hv, wv.x, acc.x);
      acc.y = fmaf(hv, wv.y, acc.y);
      acc.z = fmaf(hv, wv.z, acc.z);
      acc.w = fmaf(hv, wv.w, acc.w);
    }
  }

  if (kh == 1) *(float4*)&part[jwv][lane][0] = acc;
  __syncthreads();
  if (kh == 0) {
    const float4 p = *(const float4*)&part[jwv][lane][0];
    acc.x += p.x; acc.y += p.y; acc.z += p.z; acc.w += p.w;

    const int idx = jw * 256 + b;
    const float cold = S.c[idx];
    const float ig = sigf(acc.x), fg = sigf(acc.y);
    const float gg = tanhf(acc.z), og = sigf(acc.w);
    const float cn = fg * cold + ig * gg;
    const float hn = og * tanhf(cn);
    S.c[idx] = cn;
    S.hout[idx] = hn;
    if (S.hcopy) S.hcopy[idx] = hn;
  }
}

// ---------------------------------------------------------------------------

extern "C" void kernel_launch(void* const* d_in, const int* in_sizes, int n_in,
                              void* d_out, int out_size, void* d_ws, size_t ws_size,
                              hipStream_t stream)
{
  const float* x_in  = (const float*)d_in[0];
  const float* w_en1 = (const float*)d_in[1];
  const float* b_en1 = (const float*)d_in[2];
  const float* w_en2 = (const float*)d_in[3];
  const float* b_en2 = (const float*)d_in[4];
  const float* cw[6][4];
  for (int i = 0; i < 6; ++i)
    for (int j = 0; j < 4; ++j) cw[i][j] = (const float*)d_in[5 + i * 4 + j];
  const float* w_de1 = (const float*)d_in[29];
  const float* b_de1 = (const float*)d_in[30];
  const float* w_de2 = (const float*)d_in[31];
  const float* b_de2 = (const float*)d_in[32];
  float* out = (float*)d_out;

  // ---- workspace layout (round-13 structure, ~87 MB) ----
  float* fs   = (float*)d_ws;
  float* wihP = fs;                        // 6 * 262144 f
  float* whhP = wihP + 6 * 262144;         // 6 * 262144 f
  float* bP   = whhP + 6 * 262144;         // 6 * 1024 f
  float* hb   = bP + 6 * 1024;             // 12 * 65536 f
  float* cb   = hb + 12 * 65536;           // 6 * 65536 f
  float* H3T  = cb + 6 * 65536;            // 10 * 65536 f
  float* z2   = H3T + 10 * 65536;          // 1,310,720 f
  float* z2T  = z2 + 1310720;              // 1,310,720 f
  unsigned short* us = (unsigned short*)(z2T + 1310720);
  unsigned short* WEN1H = us;              us += 4194304;
  unsigned short* WEN1L = us;              us += 4194304;
  unsigned short* WEN2H = us;              us += 262144;
  unsigned short* WEN2L = us;              us += 262144;
  unsigned short* WDE1H = us;              us += 262144;
  unsigned short* WDE1L = us;              us += 262144;
  unsigned short* WDE2H = us;              us += 4194304;
  unsigned short* WDE2L = us;              us += 4194304;
  unsigned short* Z1H   = us;              us += 5242880;
  unsigned short* Z1L   = us;              us += 5242880;
  // Y1/H3 alias the (dead-by-then) Z1 region:
  unsigned short* H3H = Z1H;
  unsigned short* H3L = Z1H + 655360;
  unsigned short* Y1H = Z1H + 1310720;
  unsigned short* Y1L = Z1H + 1310720 + 2621440;

  // ---- prep: cell packing, weight splits, state zero (every call) ----
  for (int i = 0; i < 6; ++i)
    prep_pack<<<256, 256, 0, stream>>>(cw[i][0], cw[i][1], cw[i][2], cw[i][3],
                                       wihP + i * 262144, whhP + i * 262144,
                                       bP + i * 1024);
  wsplit<<<4096, 256, 0, stream>>>(w_en1, WEN1H, WEN1L, 1048576);
  wsplit<<<256, 256, 0, stream>>>(w_en2, WEN2H, WEN2L, 65536);
  wsplit<<<256, 256, 0, stream>>>(w_de1, WDE1H, WDE1L, 65536);
  wsplit<<<4096, 256, 0, stream>>>(w_de2, WDE2H, WDE2L, 1048576);
  hipMemsetAsync(hb, 0, (size_t)18 * 65536 * sizeof(float), stream);

  // ---- encoder feedforward (all MFMA) ----
  gemm_sf<1><<<dim3(40, 16), 256, 0, stream>>>(
      x_in, WEN1H, WEN1L, b_en1, nullptr, Z1H, Z1L, 5120, 1024, 4096, 1);
  gemm_bb<0><<<dim3(40, 4), 256, 0, stream>>>(
      Z1H, Z1L, WEN2H, WEN2L, b_en2, z2, nullptr, nullptr, 5120, 256, 1024, 1);
  transpose256<<<dim3(20, 64), 256, 0, stream>>>(z2, z2T);

  // ---- recurrence: layer-pipelined cell launches (k-split=2 blocks) ----
  int pp[6] = {0, 0, 0, 0, 0, 0};
  auto HBuf = [&](int l, int p) { return hb + (size_t)(l * 2 + p) * 65536; };
  auto CBuf = [&](int l) { return cb + (size_t)l * 65536; };
  auto WI = [&](int l) { return wihP + (size_t)l * 262144; };
  auto WHp = [&](int l) { return whhP + (size_t)l * 262144; };
  auto BB = [&](int l) { return bP + (size_t)l * 1024; };

  for (int s = 0; s <= 21; ++s) {
    CellArgs a; int n = 0; int tog[3]; int nt = 0;
    if (s < 20) {
      a.s[n++] = {z2T + (size_t)s * 65536, WI(0), WHp(0), BB(0),
                  HBuf(0, pp[0]), CBuf(0), HBuf(0, pp[0] ^ 1), nullptr, 1};
      tog[nt++] = 0;
    }
    if (s >= 1 && s <= 20) {
      a.s[n++] = {HBuf(0, pp[0]), WI(1), WHp(1), BB(1),
                  HBuf(1, pp[1]), CBuf(1), HBuf(1, pp[1] ^ 1), nullptr, 1};
      tog[nt++] = 1;
    }
    if (s >= 2) {
      a.s[n++] = {HBuf(1, pp[1]), WI(2), WHp(2), BB(2),
                  HBuf(2, pp[2]), CBuf(2), HBuf(2, pp[2] ^ 1), nullptr, 1};
      tog[nt++] = 2;
    }
    cell_multi<<<n * 256, 512, 0, stream>>>(a);
    for (int i = 0; i < nt; ++i) pp[tog[i]] ^= 1;
  }

  for (int s = 0; s <= 11; ++s) {
    CellArgs a; int n = 0; int tog[3]; int nt = 0;
    if (s < 10) {
      const float* h1in = (s == 0) ? HBuf(2, pp[2]) : HBuf(3, pp[3]);
      a.s[n++] = {nullptr, WI(3), WHp(3), BB(3),
                  h1in, CBuf(3), HBuf(3, pp[3] ^ 1), nullptr, 0};
      tog[nt++] = 3;
    }
    if (s >= 1 && s <= 10) {
      a.s[n++] = {HBuf(3, pp[3]), WI(4), WHp(4), BB(4),
                  HBuf(4, pp[4]), CBuf(4), HBuf(4, pp[4] ^ 1), nullptr, 1};
      tog[nt++] = 4;
    }
    if (s >= 2) {
      a.s[n++] = {HBuf(4, pp[4]), WI(5), WHp(5), BB(5),
                  HBuf(5, pp[5]), CBuf(5), HBuf(5, pp[5] ^ 1),
                  H3T + (size_t)(s - 2) * 65536, 1};
      tog[nt++] = 5;
    }
    cell_multi<<<n * 256, 512, 0, stream>>>(a);
    for (int i = 0; i < nt; ++i) pp[tog[i]] ^= 1;
  }

  // ---- decoder output FCs (all MFMA) ----
  transpose256s<<<dim3(10, 64), 256, 0, stream>>>(H3T, H3H, H3L);  // [s][j][b]->[s][b][j]
  gemm_bb<1><<<dim3(20, 16), 256, 0, stream>>>(
      H3H, H3L, WDE1H, WDE1L, b_de1, nullptr, Y1H, Y1L, 2560, 1024, 256, 1);
  gemm_bb<0><<<dim3(20, 64), 256, 0, stream>>>(
      Y1H, Y1L, WDE2H, WDE2L, b_de2, out, nullptr, nullptr, 2560, 4096, 1024, 2);

  (void)in_sizes; (void)n_in; (void)out_size; (void)ws_size;
}